// Round 1
// baseline (202.745 us; speedup 1.0000x reference)
//
#include <hip/hip_runtime.h>
#include <hip/hip_bf16.h>
#include <stdint.h>

// B=8, S=2048, D=256. out[b,d] = (1/S) sum_k w_k v[b,k,d],
// w_k = sum_q exp(s_qk)/l_q, l_q = sum_k' exp(s_qk') over unmasked keys.
// Two-pass QK^T in bf16 MFMA; no PV matmul needed (mean over queries).

typedef short short8 __attribute__((ext_vector_type(8)));
typedef float floatx4 __attribute__((ext_vector_type(4)));

#define MFMA16(a, b, c) __builtin_amdgcn_mfma_f32_16x16x32_bf16((a), (b), (c), 0, 0, 0)

static __device__ __forceinline__ unsigned short f2bf(float f) {
    union { float f; unsigned u; } v; v.f = f;
    unsigned r = v.u + 0x7fffu + ((v.u >> 16) & 1u);
    return (unsigned short)(r >> 16);
}
static __device__ __forceinline__ float bf2f(unsigned short h) {
    union { unsigned u; float f; } v; v.u = ((unsigned)h) << 16;
    return v.f;
}

// ---------------- k0: fp32 -> bf16 conversion (nodes + 3 weight mats) -------
__global__ __launch_bounds__(256) void k_convert(
    const float* __restrict__ nodes, const float* __restrict__ Wq,
    const float* __restrict__ Wk, const float* __restrict__ Wv,
    unsigned short* __restrict__ nbf, unsigned short* __restrict__ wbf)
{
    int unit = blockIdx.x * 256 + threadIdx.x;   // one unit = 8 elements
    const float* src;
    unsigned short* dst;
    int off;
    if (unit < 524288) {                          // 4194304 node elems
        src = nodes; dst = nbf; off = unit * 8;
    } else {
        int j = (unit - 524288) * 8;              // 0..196600, weight elem idx
        int m = j >> 16;                          // which matrix
        int r = j & 65535;
        src = (m == 0) ? Wq : (m == 1 ? Wk : Wv);
        dst = wbf + m * 65536;
        off = r;
    }
    float4 a = *(const float4*)(src + off);
    float4 b = *(const float4*)(src + off + 4);
    short8 o;
    o[0] = f2bf(a.x); o[1] = f2bf(a.y); o[2] = f2bf(a.z); o[3] = f2bf(a.w);
    o[4] = f2bf(b.x); o[5] = f2bf(b.y); o[6] = f2bf(b.z); o[7] = f2bf(b.w);
    *(short8*)(dst + off) = o;
}

// ---------------- k1: projection GEMM  out[s,e] = nodes[s,:]·W[e,:] + b[e] --
// grid (M/64, N/64, 3); block 256 = 4 waves; wave computes 32x32.
__global__ __launch_bounds__(256) void k_proj(
    const unsigned short* __restrict__ nbf,   // [16384][256] bf16
    const unsigned short* __restrict__ wbf,   // [3][256][256] bf16
    const float* __restrict__ bq, const float* __restrict__ bk,
    const float* __restrict__ bv,
    unsigned short* __restrict__ qb, unsigned short* __restrict__ kb,
    unsigned short* __restrict__ vb)
{
    int tid = threadIdx.x;
    int lane = tid & 63;
    int wave = tid >> 6;
    int wm = wave & 1, wn = wave >> 1;
    int mBase = blockIdx.x * 64 + wm * 32;
    int nBase = blockIdx.y * 64 + wn * 32;
    int z = blockIdx.z;
    const unsigned short* W = wbf + z * 65536;
    const float* bias = (z == 0) ? bq : (z == 1 ? bk : bv);
    unsigned short* out = (z == 0) ? qb : (z == 1 ? kb : vb);
    float scale = (z == 0) ? 0.0625f : 1.0f;   // fold 1/sqrt(256) into q

    int l15 = lane & 15, quad = lane >> 4;
    floatx4 acc[2][2] = {};
#pragma unroll
    for (int ks = 0; ks < 8; ++ks) {
        int koff = ks * 32 + quad * 8;
        short8 a0 = *(const short8*)(nbf + (mBase + l15) * 256 + koff);
        short8 a1 = *(const short8*)(nbf + (mBase + 16 + l15) * 256 + koff);
        short8 b0 = *(const short8*)(W + (nBase + l15) * 256 + koff);
        short8 b1 = *(const short8*)(W + (nBase + 16 + l15) * 256 + koff);
        acc[0][0] = MFMA16(a0, b0, acc[0][0]);
        acc[0][1] = MFMA16(a0, b1, acc[0][1]);
        acc[1][0] = MFMA16(a1, b0, acc[1][0]);
        acc[1][1] = MFMA16(a1, b1, acc[1][1]);
    }
#pragma unroll
    for (int mi = 0; mi < 2; ++mi)
#pragma unroll
        for (int ni = 0; ni < 2; ++ni) {
            int col = nBase + ni * 16 + l15;
            float bval = bias[col];
#pragma unroll
            for (int r = 0; r < 4; ++r) {
                int row = mBase + mi * 16 + quad * 4 + r;
                out[row * 256 + col] = f2bf((acc[mi][ni][r] + bval) * scale);
            }
        }
}

// ---------------- pass kernels: QK^T, softmax stats / weight accumulation ---
// grid (16, 4, 8): (query tile of 128, key-split of 512, batch)
// block 256 = 4 waves; wave owns 32 queries (2 m-tiles), Q frags in regs.
#define LDSW 264   // ushorts per LDS K row (256 + 8 pad -> 528B)

__global__ __launch_bounds__(256) void k_pass1(
    const unsigned short* __restrict__ qb, const unsigned short* __restrict__ kb,
    const int* __restrict__ mask, float* __restrict__ lsum_g)
{
    __shared__ unsigned short kt[64 * LDSW];
    __shared__ float mf[64];
    int tid = threadIdx.x, lane = tid & 63, wave = tid >> 6;
    int l15 = lane & 15, quad = lane >> 4;
    int b = blockIdx.z;
    int qBase = blockIdx.x * 128 + wave * 32;
    int kStart = blockIdx.y * 512;

    short8 qf[2][8];
#pragma unroll
    for (int mi = 0; mi < 2; ++mi)
#pragma unroll
        for (int ks = 0; ks < 8; ++ks)
            qf[mi][ks] = *(const short8*)(qb + (b * 2048 + qBase + mi * 16 + l15) * 256 + ks * 32 + quad * 8);

    float ls[2][4] = {};
    for (int kc = kStart; kc < kStart + 512; kc += 64) {
#pragma unroll
        for (int u = tid; u < 2048; u += 256) {       // 64 rows x 32 units
            int row = u >> 5, cu = u & 31;
            *(uint4*)(&kt[row * LDSW + cu * 8]) = *(const uint4*)(kb + (b * 2048 + kc) * 256 + u * 8);
        }
        if (tid < 64) mf[tid] = mask[b * 2048 + kc + tid] ? 1.0f : 0.0f;
        __syncthreads();
#pragma unroll
        for (int nt = 0; nt < 4; ++nt) {
            short8 kf[8];
            const unsigned short* base = &kt[(nt * 16 + l15) * LDSW + quad * 8];
#pragma unroll
            for (int ks = 0; ks < 8; ++ks) kf[ks] = *(const short8*)(base + ks * 32);
            floatx4 acc[2] = {};
#pragma unroll
            for (int ks = 0; ks < 8; ++ks) {
                acc[0] = MFMA16(qf[0][ks], kf[ks], acc[0]);
                acc[1] = MFMA16(qf[1][ks], kf[ks], acc[1]);
            }
            float mv = mf[nt * 16 + l15];
#pragma unroll
            for (int mi = 0; mi < 2; ++mi)
#pragma unroll
                for (int r = 0; r < 4; ++r)
                    ls[mi][r] += mv * __expf(fminf(acc[mi][r], 30.f));
        }
        __syncthreads();
    }
#pragma unroll
    for (int mi = 0; mi < 2; ++mi)
#pragma unroll
        for (int r = 0; r < 4; ++r) {
            float v = ls[mi][r];
            v += __shfl_xor(v, 1); v += __shfl_xor(v, 2);
            v += __shfl_xor(v, 4); v += __shfl_xor(v, 8);
            if (l15 == 0)
                atomicAdd(&lsum_g[b * 2048 + qBase + mi * 16 + quad * 4 + r], v);
        }
}

__global__ __launch_bounds__(256) void k_pass2(
    const unsigned short* __restrict__ qb, const unsigned short* __restrict__ kb,
    const int* __restrict__ mask, const float* __restrict__ lsum_g,
    float* __restrict__ wsum_g)
{
    __shared__ unsigned short kt[64 * LDSW];
    __shared__ float mf[64];
    int tid = threadIdx.x, lane = tid & 63, wave = tid >> 6;
    int l15 = lane & 15, quad = lane >> 4;
    int b = blockIdx.z;
    int qBase = blockIdx.x * 128 + wave * 32;
    int kStart = blockIdx.y * 512;

    short8 qf[2][8];
    float linv[2][4];
#pragma unroll
    for (int mi = 0; mi < 2; ++mi) {
#pragma unroll
        for (int ks = 0; ks < 8; ++ks)
            qf[mi][ks] = *(const short8*)(qb + (b * 2048 + qBase + mi * 16 + l15) * 256 + ks * 32 + quad * 8);
#pragma unroll
        for (int r = 0; r < 4; ++r)
            linv[mi][r] = 1.0f / lsum_g[b * 2048 + qBase + mi * 16 + quad * 4 + r];
    }

    for (int kc = kStart; kc < kStart + 512; kc += 64) {
#pragma unroll
        for (int u = tid; u < 2048; u += 256) {
            int row = u >> 5, cu = u & 31;
            *(uint4*)(&kt[row * LDSW + cu * 8]) = *(const uint4*)(kb + (b * 2048 + kc) * 256 + u * 8);
        }
        if (tid < 64) mf[tid] = mask[b * 2048 + kc + tid] ? 1.0f : 0.0f;
        __syncthreads();
#pragma unroll
        for (int nt = 0; nt < 4; ++nt) {
            short8 kf[8];
            const unsigned short* base = &kt[(nt * 16 + l15) * LDSW + quad * 8];
#pragma unroll
            for (int ks = 0; ks < 8; ++ks) kf[ks] = *(const short8*)(base + ks * 32);
            floatx4 acc[2] = {};
#pragma unroll
            for (int ks = 0; ks < 8; ++ks) {
                acc[0] = MFMA16(qf[0][ks], kf[ks], acc[0]);
                acc[1] = MFMA16(qf[1][ks], kf[ks], acc[1]);
            }
            float mv = mf[nt * 16 + l15];
            float part = 0.f;
#pragma unroll
            for (int mi = 0; mi < 2; ++mi)
#pragma unroll
                for (int r = 0; r < 4; ++r)
                    part += mv * __expf(fminf(acc[mi][r], 30.f)) * linv[mi][r];
            part += __shfl_xor(part, 16);
            part += __shfl_xor(part, 32);
            if (lane < 16)
                atomicAdd(&wsum_g[b * 2048 + kc + nt * 16 + lane], part);
        }
        __syncthreads();
    }
}

// ---------------- k4: out[b,d] = (1/S) sum_k w[b,k] * v[b,k,d] --------------
__global__ __launch_bounds__(256) void k_out(
    const float* __restrict__ wsum_g, const unsigned short* __restrict__ vb,
    float* __restrict__ outp)
{
    int b = blockIdx.y;
    int d = threadIdx.x;
    int k0 = blockIdx.x * 128;
    float acc = 0.f;
#pragma unroll 4
    for (int k = k0; k < k0 + 128; ++k) {
        float wv = wsum_g[b * 2048 + k];
        acc += wv * bf2f(vb[(b * 2048 + k) * 256 + d]);
    }
    atomicAdd(&outp[b * 256 + d], acc * (1.0f / 2048.0f));
}

extern "C" void kernel_launch(void* const* d_in, const int* in_sizes, int n_in,
                              void* d_out, int out_size, void* d_ws, size_t ws_size,
                              hipStream_t stream)
{
    const float* nodes = (const float*)d_in[0];
    const int*   mask  = (const int*)d_in[1];
    const float* Wq    = (const float*)d_in[2];
    const float* bq    = (const float*)d_in[3];
    const float* Wk    = (const float*)d_in[4];
    const float* bk    = (const float*)d_in[5];
    const float* Wv    = (const float*)d_in[6];
    const float* bv    = (const float*)d_in[7];
    float* out = (float*)d_out;

    // workspace layout (bf16 stored as ushort)
    unsigned short* qb  = (unsigned short*)d_ws;        // 16384*256
    unsigned short* kb  = qb + 4194304;
    unsigned short* vb  = kb + 4194304;
    unsigned short* nbf = vb + 4194304;
    unsigned short* wbf = nbf + 4194304;                // 3*65536
    float* lsum = (float*)(wbf + 196608);               // 16384
    float* wsum = lsum + 16384;                         // 16384

    hipMemsetAsync(lsum, 0, 16384 * sizeof(float), stream);
    hipMemsetAsync(wsum, 0, 16384 * sizeof(float), stream);
    hipMemsetAsync(d_out, 0, 2048 * sizeof(float), stream);

    k_convert<<<2144, 256, 0, stream>>>(nodes, Wq, Wk, Wv, nbf, wbf);
    k_proj<<<dim3(256, 4, 3), 256, 0, stream>>>(nbf, wbf, bq, bk, bv, qb, kb, vb);
    k_pass1<<<dim3(16, 4, 8), 256, 0, stream>>>(qb, kb, mask, lsum);
    k_pass2<<<dim3(16, 4, 8), 256, 0, stream>>>(qb, kb, mask, lsum, wsum);
    k_out<<<dim3(16, 8), 256, 0, stream>>>(wsum, vb, out);
}

// Round 2
// 155.933 us; speedup vs baseline: 1.3002x; 1.3002x over previous
//
#include <hip/hip_runtime.h>
#include <hip/hip_bf16.h>
#include <stdint.h>

// B=8, S=2048, D=256. out[b,d] = (1/S) sum_k w_k v[b,k,d],
// w_k = sum_q P_qk / l_q,  P_qk = exp(s_qk) (0 for masked k), l_q = sum_k P_qk.
// pass1: QK^T bf16 MFMA -> P (fp16, cached) + l_q.  k_wred: column-reduce P.
// Fallback (small ws): recompute QK^T in pass2 (round-1 proven path).

typedef short short8 __attribute__((ext_vector_type(8)));
typedef float floatx4 __attribute__((ext_vector_type(4)));

#define MFMA16(a, b, c) __builtin_amdgcn_mfma_f32_16x16x32_bf16((a), (b), (c), 0, 0, 0)

static __device__ __forceinline__ unsigned short f2bf(float f) {
    union { float f; unsigned u; } v; v.f = f;
    unsigned r = v.u + 0x7fffu + ((v.u >> 16) & 1u);
    return (unsigned short)(r >> 16);
}
static __device__ __forceinline__ float bf2f(unsigned short h) {
    union { unsigned u; float f; } v; v.u = ((unsigned)h) << 16;
    return v.f;
}

// ---------------- k0: fp32 -> bf16 conversion (nodes + 3 weight mats) -------
__global__ __launch_bounds__(256) void k_convert(
    const float* __restrict__ nodes, const float* __restrict__ Wq,
    const float* __restrict__ Wk, const float* __restrict__ Wv,
    unsigned short* __restrict__ nbf, unsigned short* __restrict__ wbf)
{
    int unit = blockIdx.x * 256 + threadIdx.x;   // one unit = 8 elements
    const float* src;
    unsigned short* dst;
    int off;
    if (unit < 524288) {                          // 4194304 node elems
        src = nodes; dst = nbf; off = unit * 8;
    } else {
        int j = (unit - 524288) * 8;              // weight elem idx
        int m = j >> 16;                          // which matrix
        int r = j & 65535;
        src = (m == 0) ? Wq : (m == 1 ? Wk : Wv);
        dst = wbf + m * 65536;
        off = r;
    }
    float4 a = *(const float4*)(src + off);
    float4 b = *(const float4*)(src + off + 4);
    short8 o;
    o[0] = f2bf(a.x); o[1] = f2bf(a.y); o[2] = f2bf(a.z); o[3] = f2bf(a.w);
    o[4] = f2bf(b.x); o[5] = f2bf(b.y); o[6] = f2bf(b.z); o[7] = f2bf(b.w);
    *(short8*)(dst + off) = o;
}

// ---------------- k1: projection GEMM, 128x128 LDS-tiled --------------------
// grid (128, 2, 3); block 256 = 4 waves (2x2), wave computes 64x64.
// LDS layout: 16B chunks, slot p holds tile chunk (row=p>>3, col8=(p&7)^(row&7))
// -> ds_write conflict-free (contiguous per wave), ds_read 2-way (free).
__global__ __launch_bounds__(256) void k_proj2(
    const unsigned short* __restrict__ nbf,   // [16384][256] bf16
    const unsigned short* __restrict__ wbf,   // [3][256][256] bf16
    const float* __restrict__ bq, const float* __restrict__ bk,
    const float* __restrict__ bv,
    unsigned short* __restrict__ qb, unsigned short* __restrict__ kb,
    unsigned short* __restrict__ vb)
{
    __shared__ unsigned short As[128 * 64];   // 1024 chunks of 16B
    __shared__ unsigned short Bs[128 * 64];
    int tid = threadIdx.x, lane = tid & 63, wave = tid >> 6;
    int wm = wave & 1, wn = wave >> 1;
    int l15 = lane & 15, quad = lane >> 4;
    int mBase = blockIdx.x * 128;
    int nBase = blockIdx.y * 128;
    int z = blockIdx.z;
    const unsigned short* W = wbf + z * 65536;

    floatx4 acc[4][4] = {};

    // staging map: pass i, slot p = i*256+tid; row=p>>3, col8=(p&7)^(row&7)
    int srow[4], scol[4];
#pragma unroll
    for (int i = 0; i < 4; ++i) {
        int p = i * 256 + tid;
        srow[i] = p >> 3;
        scol[i] = (p & 7) ^ (srow[i] & 7);
    }

    for (int kc = 0; kc < 256; kc += 64) {
#pragma unroll
        for (int i = 0; i < 4; ++i) {
            int p = i * 256 + tid;
            *(short8*)(&As[p * 8]) =
                *(const short8*)(nbf + (mBase + srow[i]) * 256 + kc + scol[i] * 8);
            *(short8*)(&Bs[p * 8]) =
                *(const short8*)(W + (nBase + srow[i]) * 256 + kc + scol[i] * 8);
        }
        __syncthreads();
#pragma unroll
        for (int ks = 0; ks < 2; ++ks) {
            int c8 = ks * 4 + quad;
            short8 af[4], bfr[4];
#pragma unroll
            for (int i = 0; i < 4; ++i) {
                int row = wm * 64 + i * 16 + l15;
                af[i] = *(const short8*)(&As[(row * 8 + (c8 ^ (row & 7))) * 8]);
            }
#pragma unroll
            for (int i = 0; i < 4; ++i) {
                int row = wn * 64 + i * 16 + l15;
                bfr[i] = *(const short8*)(&Bs[(row * 8 + (c8 ^ (row & 7))) * 8]);
            }
#pragma unroll
            for (int mi = 0; mi < 4; ++mi)
#pragma unroll
                for (int ni = 0; ni < 4; ++ni)
                    acc[mi][ni] = MFMA16(af[mi], bfr[ni], acc[mi][ni]);
        }
        __syncthreads();
    }

    const float* bias = (z == 0) ? bq : (z == 1 ? bk : bv);
    unsigned short* out = (z == 0) ? qb : (z == 1 ? kb : vb);
    float scale = (z == 0) ? 0.0625f : 1.0f;   // fold 1/sqrt(256) into q
#pragma unroll
    for (int mi = 0; mi < 4; ++mi)
#pragma unroll
        for (int ni = 0; ni < 4; ++ni) {
            int col = nBase + wn * 64 + ni * 16 + l15;
            float bval = bias[col];
#pragma unroll
            for (int r = 0; r < 4; ++r) {
                int row = mBase + wm * 64 + mi * 16 + quad * 4 + r;
                out[row * 256 + col] = f2bf((acc[mi][ni][r] + bval) * scale);
            }
        }
}

// ---------------- pass1: QK^T, exp, l_q; optionally cache P fp16 ------------
// grid (16, 4, 8); block 256 = 4 waves; wave owns 32 queries.
#define LDSW 264   // ushorts per LDS K row (256 + 8 pad)

template <bool STORE_P>
__global__ __launch_bounds__(256) void k_pass1(
    const unsigned short* __restrict__ qb, const unsigned short* __restrict__ kb,
    const int* __restrict__ mask, float* __restrict__ lsum_g,
    unsigned short* __restrict__ pbuf)
{
    __shared__ unsigned short kt[64 * LDSW];
    __shared__ float mf[64];
    int tid = threadIdx.x, lane = tid & 63, wave = tid >> 6;
    int l15 = lane & 15, quad = lane >> 4;
    int b = blockIdx.z;
    int qBase = blockIdx.x * 128 + wave * 32;
    int kStart = blockIdx.y * 512;
    _Float16* P = (_Float16*)pbuf;

    short8 qf[2][8];
#pragma unroll
    for (int mi = 0; mi < 2; ++mi)
#pragma unroll
        for (int ks = 0; ks < 8; ++ks)
            qf[mi][ks] = *(const short8*)(qb + (b * 2048 + qBase + mi * 16 + l15) * 256 + ks * 32 + quad * 8);

    float ls[2][4] = {};
    for (int kc = kStart; kc < kStart + 512; kc += 64) {
#pragma unroll
        for (int u = tid; u < 2048; u += 256) {
            int row = u >> 5, cu = u & 31;
            *(uint4*)(&kt[row * LDSW + cu * 8]) = *(const uint4*)(kb + (b * 2048 + kc) * 256 + u * 8);
        }
        if (tid < 64) mf[tid] = mask[b * 2048 + kc + tid] ? 0.0f : -1e30f;
        __syncthreads();
#pragma unroll
        for (int nt = 0; nt < 4; ++nt) {
            short8 kf[8];
            const unsigned short* base = &kt[(nt * 16 + l15) * LDSW + quad * 8];
#pragma unroll
            for (int ks = 0; ks < 8; ++ks) kf[ks] = *(const short8*)(base + ks * 32);
            floatx4 acc[2] = {};
#pragma unroll
            for (int ks = 0; ks < 8; ++ks) {
                acc[0] = MFMA16(qf[0][ks], kf[ks], acc[0]);
                acc[1] = MFMA16(qf[1][ks], kf[ks], acc[1]);
            }
            float bv = mf[nt * 16 + l15];
#pragma unroll
            for (int mi = 0; mi < 2; ++mi)
#pragma unroll
                for (int r = 0; r < 4; ++r) {
                    float e = __expf(acc[mi][r] + bv);
                    ls[mi][r] += e;
                    if (STORE_P) {
                        int q = qBase + mi * 16 + quad * 4 + r;
                        P[(b * 2048 + q) * 2048 + kc + nt * 16 + l15] = (_Float16)e;
                    }
                }
        }
        __syncthreads();
    }
#pragma unroll
    for (int mi = 0; mi < 2; ++mi)
#pragma unroll
        for (int r = 0; r < 4; ++r) {
            float v = ls[mi][r];
            v += __shfl_xor(v, 1); v += __shfl_xor(v, 2);
            v += __shfl_xor(v, 4); v += __shfl_xor(v, 8);
            if (l15 == 0)
                atomicAdd(&lsum_g[b * 2048 + qBase + mi * 16 + quad * 4 + r], v);
        }
}

// ---------------- k_wred: w_k = sum_q P[b][q][k] / l_q  (P path) ------------
// grid (4, 16, 8); thread handles 2 keys, 128 queries per block.
__global__ __launch_bounds__(256) void k_wred(
    const unsigned short* __restrict__ pbuf, const float* __restrict__ lsum_g,
    float* __restrict__ wsum_g)
{
    int b = blockIdx.z;
    int k = (blockIdx.x * 256 + threadIdx.x) * 2;
    int q0 = blockIdx.y * 128;
    const unsigned short* P = pbuf;
    float a0 = 0.f, a1 = 0.f;
#pragma unroll 8
    for (int q = q0; q < q0 + 128; ++q) {
        float li = 1.0f / lsum_g[b * 2048 + q];
        union { unsigned u; _Float16 h[2]; } v;
        v.u = *(const unsigned*)(P + (b * 2048 + q) * 2048 + k);
        a0 += (float)v.h[0] * li;
        a1 += (float)v.h[1] * li;
    }
    atomicAdd(&wsum_g[b * 2048 + k], a0);
    atomicAdd(&wsum_g[b * 2048 + k + 1], a1);
}

// ---------------- pass2 (fallback, recompute): proven round-1 path ----------
__global__ __launch_bounds__(256) void k_pass2(
    const unsigned short* __restrict__ qb, const unsigned short* __restrict__ kb,
    const int* __restrict__ mask, const float* __restrict__ lsum_g,
    float* __restrict__ wsum_g)
{
    __shared__ unsigned short kt[64 * LDSW];
    __shared__ float mf[64];
    int tid = threadIdx.x, lane = tid & 63, wave = tid >> 6;
    int l15 = lane & 15, quad = lane >> 4;
    int b = blockIdx.z;
    int qBase = blockIdx.x * 128 + wave * 32;
    int kStart = blockIdx.y * 512;

    short8 qf[2][8];
    float linv[2][4];
#pragma unroll
    for (int mi = 0; mi < 2; ++mi) {
#pragma unroll
        for (int ks = 0; ks < 8; ++ks)
            qf[mi][ks] = *(const short8*)(qb + (b * 2048 + qBase + mi * 16 + l15) * 256 + ks * 32 + quad * 8);
#pragma unroll
        for (int r = 0; r < 4; ++r)
            linv[mi][r] = 1.0f / lsum_g[b * 2048 + qBase + mi * 16 + quad * 4 + r];
    }

    for (int kc = kStart; kc < kStart + 512; kc += 64) {
#pragma unroll
        for (int u = tid; u < 2048; u += 256) {
            int row = u >> 5, cu = u & 31;
            *(uint4*)(&kt[row * LDSW + cu * 8]) = *(const uint4*)(kb + (b * 2048 + kc) * 256 + u * 8);
        }
        if (tid < 64) mf[tid] = mask[b * 2048 + kc + tid] ? 1.0f : 0.0f;
        __syncthreads();
#pragma unroll
        for (int nt = 0; nt < 4; ++nt) {
            short8 kf[8];
            const unsigned short* base = &kt[(nt * 16 + l15) * LDSW + quad * 8];
#pragma unroll
            for (int ks = 0; ks < 8; ++ks) kf[ks] = *(const short8*)(base + ks * 32);
            floatx4 acc[2] = {};
#pragma unroll
            for (int ks = 0; ks < 8; ++ks) {
                acc[0] = MFMA16(qf[0][ks], kf[ks], acc[0]);
                acc[1] = MFMA16(qf[1][ks], kf[ks], acc[1]);
            }
            float mv = mf[nt * 16 + l15];
            float part = 0.f;
#pragma unroll
            for (int mi = 0; mi < 2; ++mi)
#pragma unroll
                for (int r = 0; r < 4; ++r)
                    part += mv * __expf(fminf(acc[mi][r], 30.f)) * linv[mi][r];
            part += __shfl_xor(part, 16);
            part += __shfl_xor(part, 32);
            if (lane < 16)
                atomicAdd(&wsum_g[b * 2048 + kc + nt * 16 + lane], part);
        }
        __syncthreads();
    }
}

// ---------------- k4: out[b,d] = (1/S) sum_k w[b,k] * v[b,k,d] --------------
__global__ __launch_bounds__(256) void k_out(
    const float* __restrict__ wsum_g, const unsigned short* __restrict__ vb,
    float* __restrict__ outp)
{
    int b = blockIdx.y;
    int d = threadIdx.x;
    int k0 = blockIdx.x * 128;
    float acc = 0.f;
#pragma unroll 4
    for (int k = k0; k < k0 + 128; ++k) {
        float wv = wsum_g[b * 2048 + k];
        acc += wv * bf2f(vb[(b * 2048 + k) * 256 + d]);
    }
    atomicAdd(&outp[b * 256 + d], acc * (1.0f / 2048.0f));
}

extern "C" void kernel_launch(void* const* d_in, const int* in_sizes, int n_in,
                              void* d_out, int out_size, void* d_ws, size_t ws_size,
                              hipStream_t stream)
{
    const float* nodes = (const float*)d_in[0];
    const int*   mask  = (const int*)d_in[1];
    const float* Wq    = (const float*)d_in[2];
    const float* bq    = (const float*)d_in[3];
    const float* Wk    = (const float*)d_in[4];
    const float* bk    = (const float*)d_in[5];
    const float* Wv    = (const float*)d_in[6];
    const float* bv    = (const float*)d_in[7];
    float* out = (float*)d_out;

    // workspace layout (ushort units). Region X holds nbf+wbf (convert/proj
    // lifetime) and is later reused for P (pass1 onward) in the P path.
    unsigned short* qb  = (unsigned short*)d_ws;        // 16384*256
    unsigned short* kb  = qb + 4194304;
    unsigned short* vb  = kb + 4194304;
    float* lsum = (float*)(vb + 4194304);               // 16384
    float* wsum = lsum + 16384;                         // 16384
    unsigned short* X   = (unsigned short*)(wsum + 16384);
    unsigned short* nbf = X;                            // 4194304
    unsigned short* wbf = X + 4194304;                  // 196608
    unsigned short* pbuf = X;                           // 33554432 (P path)

    bool useP = ws_size >= 92500000;   // 25.3 MB fixed + 67 MB P

    hipMemsetAsync(lsum, 0, 16384 * sizeof(float), stream);
    hipMemsetAsync(wsum, 0, 16384 * sizeof(float), stream);
    hipMemsetAsync(d_out, 0, 2048 * sizeof(float), stream);

    k_convert<<<2144, 256, 0, stream>>>(nodes, Wq, Wk, Wv, nbf, wbf);
    k_proj2<<<dim3(128, 2, 3), 256, 0, stream>>>(nbf, wbf, bq, bk, bv, qb, kb, vb);
    if (useP) {
        k_pass1<true><<<dim3(16, 4, 8), 256, 0, stream>>>(qb, kb, mask, lsum, pbuf);
        k_wred<<<dim3(4, 16, 8), 256, 0, stream>>>(pbuf, lsum, wsum);
    } else {
        k_pass1<false><<<dim3(16, 4, 8), 256, 0, stream>>>(qb, kb, mask, lsum, pbuf);
        k_pass2<<<dim3(16, 4, 8), 256, 0, stream>>>(qb, kb, mask, lsum, wsum);
    }
    k_out<<<dim3(16, 8), 256, 0, stream>>>(wsum, vb, out);
}